// Round 23
// baseline (177.936 us; speedup 1.0000x reference)
//
#include <hip/hip_runtime.h>

// Problem: B=4, S=2048, E=1024, H=16, DH=64
// out[b][s][h*64+d] = softmax_causal(Q K^T / 8) V, with Q/K/V = X @ W{q,k,v}[h]
//
// Pipeline (round-22 best = 144.2us, + 128-key attn staging epochs):
//   1) convs:  merged conv_x (f32->bf16 X) + conv_w (W -> bf16 transposed Wt)
//   2) qkv_gemm: 256x256 tile, BK=32, 3-buffer LDS ring (96KB), counted
//        vmcnt(4), 1 barrier/tile, swizzled LDS, XCD-local grid. ALL p use
//        swapped-operand MFMA (C'=[n][m]); Q/K epilogue = uint2 stores;
//        p=2 V^T key-permuted scatter ([g|sub16|r] in 32-blocks).
//   3) attn: flash, swapped-QK^T (in-register P), permuted-k PV (single
//        ds_read_b128 per V fragment), 128-KEY double-buffered staging
//        (2x 64-key compute halves per barrier -> 34 -> 17 barriers/block),
//        T14 reg prefetch, XCD-grouped grid, paired causal tiles {15-p, p},
//        cvt_pk P->bf16 pack (T12).

typedef short bf16x4 __attribute__((ext_vector_type(4)));
typedef short bf16x8 __attribute__((ext_vector_type(8)));
typedef float f32x4 __attribute__((ext_vector_type(4)));
typedef unsigned short u16x4 __attribute__((ext_vector_type(4)));
typedef unsigned short u16x8 __attribute__((ext_vector_type(8)));

#define SCL 0.1803368801111204f   /* log2(e)/8 : folds the 1/sqrt(64) into exp2 */

static __device__ __forceinline__ unsigned short f2bf(float f) {
  unsigned int u = __builtin_bit_cast(unsigned int, f);
  u += 0x7fffu + ((u >> 16) & 1u);   // RNE
  return (unsigned short)(u >> 16);
}

static __device__ __forceinline__ void gload16(const void* g, void* l) {
  __builtin_amdgcn_global_load_lds((__attribute__((address_space(1))) void*)g,
                                   (__attribute__((address_space(3))) void*)l, 16, 0, 0);
}

// ---------------- 1) merged convs ----------------
// blocks 0..767:    conv_w  (p = bid/256, h/et from bid%256)
// blocks 768..2815: conv_x  (grid-stride over 2M float4 chunks)
__global__ __launch_bounds__(256) void convs(const float* __restrict__ x,
                                             const float* __restrict__ Wq,
                                             const float* __restrict__ Wk,
                                             const float* __restrict__ Wv,
                                             unsigned short* __restrict__ Xb,
                                             unsigned short* __restrict__ Wt) {
  const int bid = blockIdx.x;
  const int t = threadIdx.x;
  if (bid < 768) {
    __shared__ __align__(16) unsigned short tile[64][72];  // [e][d], padded
    const int p = bid >> 8, he = bid & 255;
    const float* Wsrc = (p == 0) ? Wq : ((p == 1) ? Wk : Wv);
    const int h = he >> 4, et = he & 15;                   // 64-wide e tile
    const float* src = Wsrc + (h * 1024 + et * 64) * 64;   // rows e (64), cols d (64)
#pragma unroll
    for (int i = 0; i < 4; ++i) {
      int c = i * 256 + t;
      int r = c >> 4, cc = (c & 15) * 4;
      float4 v = *(const float4*)(src + r * 64 + cc);
      tile[r][cc + 0] = f2bf(v.x); tile[r][cc + 1] = f2bf(v.y);
      tile[r][cc + 2] = f2bf(v.z); tile[r][cc + 3] = f2bf(v.w);
    }
    __syncthreads();
#pragma unroll
    for (int i = 0; i < 2; ++i) {
      int c = i * 256 + t;
      int d = c >> 3, ec = (c & 7) * 8;
      u16x8 o;
#pragma unroll
      for (int j = 0; j < 8; ++j) o[j] = tile[ec + j][d];
      *(u16x8*)(Wt + (p * 1024 + h * 64 + d) * 1024 + et * 64 + ec) = o;
    }
  } else {
    const int n4 = 2097152;
    int i0 = (bid - 768) * 256 + t;
    const int stride = 2048 * 256;
    for (int c = i0; c < n4; c += stride) {
      float4 v = ((const float4*)x)[c];
      u16x4 o;
      o[0] = f2bf(v.x); o[1] = f2bf(v.y); o[2] = f2bf(v.z); o[3] = f2bf(v.w);
      ((u16x4*)Xb)[c] = o;
    }
  }
}

// ---------------- 2) QKV GEMM: 256x256, BK=32, 3-buf ring, unified swapped MFMA ----------------
__global__ __launch_bounds__(512, 2) void qkv_gemm(const unsigned short* __restrict__ Xb,
                                                   const unsigned short* __restrict__ Wt,
                                                   unsigned short* __restrict__ Qb,
                                                   unsigned short* __restrict__ Kb,
                                                   unsigned short* __restrict__ Vtb) {
  __shared__ __align__(16) unsigned short L[3][2][256 * 32];  // [buf][A/B][row*32+chunk*8]

  const int t = threadIdx.x, lane = t & 63, w = t >> 6;
  const int wr = w >> 2, wc = w & 3, c16 = lane & 15, g = lane >> 4;

  const int bid = blockIdx.x;
  const int xcd = bid & 7, l = bid >> 3;        // l in 0..47
  const int nt = l >> 2;                        // 0..11
  const int m0 = (xcd * 4 + (l & 3)) * 256;     // XCD-local m stripe
  const int p = nt >> 2;                        // 0..2 (Q/K/V)
  const int nb0 = (nt & 3) * 256;               // n offset within the 1024 block

  f32x4 acc[8][4] = {};

  const int srow = t >> 2;
  const int scl = (t & 3) ^ ((srow & 3) ^ ((srow >> 2) & 3));  // pre-swizzled src chunk
  const int chp = (g ^ ((c16 & 3) ^ ((c16 >> 2) & 3))) * 8;

#define STAGE(KT, AB, HALF, BUF)                                                   \
  {                                                                                \
    const unsigned short* s_ =                                                     \
        (((AB) == 0) ? (Xb + (m0 + (HALF)*128) * 1024)                             \
                     : (Wt + (p * 1024 + nb0 + (HALF)*128) * 1024)) +              \
        (KT)*32 + srow * 1024 + scl * 8;                                           \
    gload16(s_, &L[BUF][AB][(HALF)*4096 + w * 512]);                               \
  }
#define LDA(BUF, MI) (*(const bf16x8*)&L[BUF][0][(wr * 128 + (MI)*16 + c16) * 32 + chp])
#define LDB(BUF, NI) (*(const bf16x8*)&L[BUF][1][(wc * 64 + (NI)*16 + c16) * 32 + chp])

  // prologue: stage tiles 0 (buf0) and 1 (buf1); 8 loads in flight
  STAGE(0, 0, 0, 0); STAGE(0, 0, 1, 0); STAGE(0, 1, 0, 0); STAGE(0, 1, 1, 0);
  STAGE(1, 0, 0, 1); STAGE(1, 0, 1, 1); STAGE(1, 1, 0, 1); STAGE(1, 1, 1, 1);

  int buf = 0;
#pragma unroll 1
  for (int kt = 0; kt < 32; ++kt) {
    const int sbuf = (buf == 0) ? 2 : buf - 1;  // slot of kt-1, freed by this barrier
    if (kt < 31) { asm volatile("s_waitcnt vmcnt(4)" ::: "memory"); }  // tile kt landed
    else         { asm volatile("s_waitcnt vmcnt(0)" ::: "memory"); }
    __builtin_amdgcn_s_barrier();

    bf16x8 bq[4], aq[4];
#pragma unroll
    for (int ni = 0; ni < 4; ++ni) bq[ni] = LDB(buf, ni);
#pragma unroll
    for (int mi = 0; mi < 4; ++mi) aq[mi] = LDA(buf, mi);
    if (kt < 30) { STAGE(kt + 2, 0, 0, sbuf); STAGE(kt + 2, 0, 1, sbuf); }
    __builtin_amdgcn_s_setprio(1);
#pragma unroll
    for (int q = 0; q < 4; ++q)
#pragma unroll
      for (int ni = 0; ni < 4; ++ni)
        acc[q][ni] = __builtin_amdgcn_mfma_f32_16x16x32_bf16(bq[ni], aq[q], acc[q][ni], 0, 0, 0);
    __builtin_amdgcn_s_setprio(0);

    bf16x8 aq2[4];
#pragma unroll
    for (int mi = 0; mi < 4; ++mi) aq2[mi] = LDA(buf, 4 + mi);
    if (kt < 30) { STAGE(kt + 2, 1, 0, sbuf); STAGE(kt + 2, 1, 1, sbuf); }
    __builtin_amdgcn_s_setprio(1);
#pragma unroll
    for (int q = 0; q < 4; ++q)
#pragma unroll
      for (int ni = 0; ni < 4; ++ni)
        acc[4 + q][ni] = __builtin_amdgcn_mfma_f32_16x16x32_bf16(bq[ni], aq2[q], acc[4 + q][ni], 0, 0, 0);
    __builtin_amdgcn_s_setprio(0);

    buf = (buf == 2) ? 0 : buf + 1;
  }

  // epilogue: C'[n][m] layout (n over g*4+r, m over c16)
  if (p != 2) {
    unsigned short* dst = (p == 0) ? Qb : Kb;
#pragma unroll
    for (int mi = 0; mi < 8; ++mi) {
      const int m_g = m0 + wr * 128 + mi * 16 + c16;              // s-dim
      const int b = m_g >> 11, s = m_g & 2047;
#pragma unroll
      for (int ni = 0; ni < 4; ++ni) {
        const int n_g0 = nb0 + wc * 64 + ni * 16 + g * 4;         // d base, r contig
        unsigned int w0, w1;
        asm("v_cvt_pk_bf16_f32 %0, %1, %2"
            : "=v"(w0) : "v"(acc[mi][ni][0]), "v"(acc[mi][ni][1]));
        asm("v_cvt_pk_bf16_f32 %0, %1, %2"
            : "=v"(w1) : "v"(acc[mi][ni][2]), "v"(acc[mi][ni][3]));
        uint2 pk; pk.x = w0; pk.y = w1;
        *(uint2*)(dst + ((b * 16 + (n_g0 >> 6)) * 2048 + s) * 64 + (n_g0 & 63)) = pk;
      }
    }
  } else {
#pragma unroll
    for (int mi = 0; mi < 8; ++mi)
#pragma unroll
      for (int ni = 0; ni < 4; ++ni)
#pragma unroll
        for (int r = 0; r < 4; ++r) {
          int n_g = nb0 + wc * 64 + ni * 16 + g * 4 + r;          // d-dim
          int m_g = m0 + wr * 128 + mi * 16 + c16;                // s-dim
          int b = m_g >> 11, s = m_g & 2047;
          // key permuted within 32-block: [g(2b) | sub16(1b) | r(2b)]
          int sp = (s & ~31) | ((s << 1) & 24) | ((s >> 2) & 4) | (s & 3);
          Vtb[((b * 16 + (n_g >> 6)) * 64 + (n_g & 63)) * 2048 + sp] = f2bf(acc[mi][ni][r]);
        }
  }
#undef STAGE
#undef LDA
#undef LDB
}

// ---------------- 3) Flash attention: 128-key epochs, swapped-QK^T, cvt_pk ----------------
// 1D grid 512. xcd = bid&7; 8 heads/XCD; 8 pair-blocks/head; pair p: {15-p, p}.
// 4 waves x 32 q-rows. Per job: npair = qt+1 epochs of 128 keys; each epoch
// stages once (4+4 uint4), computes two 64-key halves, one barrier.
// V^T arrives key-permuted (32-block internal [g|sub16|r]) -> PV fragment is
// ONE ds_read_b128.
__global__ __launch_bounds__(256) void attn(const unsigned short* __restrict__ Qb,
                                            const unsigned short* __restrict__ Kb,
                                            const unsigned short* __restrict__ Vtb,
                                            float* __restrict__ out) {
  const int bid = blockIdx.x;
  const int xcd = bid & 7, slot = bid >> 3;
  const int bh = xcd * 8 + (slot >> 3);
  const int pp = slot & 7;
  const int b = bh >> 4, h = bh & 15;
  const int t = threadIdx.x, lane = t & 63, w = t >> 6;
  const int g = lane >> 4, c = lane & 15;

  __shared__ __align__(16) unsigned short Ks[2][128][72];  // [buf][key][d] padded
  __shared__ __align__(16) unsigned short Vs[2][64][136];  // [buf][d][key-perm] padded

  for (int job = 0; job < 2; ++job) {
    const int qt = job ? pp : 15 - pp;
    const int q0 = qt * 128;
    const int npair = qt + 1;                    // 128-key epochs

    bf16x8 qf[2][2];
#pragma unroll
    for (int mi = 0; mi < 2; ++mi)
#pragma unroll
      for (int kc = 0; kc < 2; ++kc)
        qf[mi][kc] = *(const bf16x8*)(Qb + ((bh * 2048 + q0 + w * 32 + mi * 16 + c) << 6)
                                         + kc * 32 + g * 8);

    f32x4 o_acc[2][4] = {};
    float m_r[2] = {-INFINITY, -INFINITY};
    float l_r[2] = {0.f, 0.f};

    uint4 kr[4], vr[4];
    // prologue: stage epoch 0 (keys 0..127) into buf 0
#pragma unroll
    for (int i = 0; i < 4; ++i) {
      int cid = i * 256 + t;
      kr[i] = *(const uint4*)(Kb + ((bh * 2048 + (cid >> 3)) << 6) + (cid & 7) * 8);
      vr[i] = *(const uint4*)(Vtb + ((bh * 64 + (cid >> 4)) << 11) + (cid & 15) * 8);
    }
#pragma unroll
    for (int i = 0; i < 4; ++i) {
      int cid = i * 256 + t;
      *(uint4*)&Ks[0][cid >> 3][(cid & 7) * 8] = kr[i];
      *(uint4*)&Vs[0][cid >> 4][(cid & 15) * 8] = vr[i];
    }
    __syncthreads();

    for (int pr = 0; pr < npair; ++pr) {
      const int cur = pr & 1;
      // T14: issue next epoch's global loads before compute
      if (pr + 1 < npair) {
        const int kv0n = (pr + 1) * 128;
#pragma unroll
        for (int i = 0; i < 4; ++i) {
          int cid = i * 256 + t;
          kr[i] = *(const uint4*)(Kb + ((bh * 2048 + kv0n + (cid >> 3)) << 6) + (cid & 7) * 8);
          vr[i] = *(const uint4*)(Vtb + ((bh * 64 + (cid >> 4)) << 11) + kv0n + (cid & 15) * 8);
        }
      }

#pragma unroll
      for (int h64 = 0; h64 < 2; ++h64) {
        const int kt = 2 * pr + h64;           // 64-key tile index

        f32x4 sc[2][4];
#pragma unroll
        for (int sub = 0; sub < 4; ++sub) {
          bf16x8 kf0 = *(const bf16x8*)&Ks[cur][h64 * 64 + sub * 16 + c][g * 8];
          bf16x8 kf1 = *(const bf16x8*)&Ks[cur][h64 * 64 + sub * 16 + c][32 + g * 8];
#pragma unroll
          for (int mi = 0; mi < 2; ++mi) {
            f32x4 z = {};
            z = __builtin_amdgcn_mfma_f32_16x16x32_bf16(kf0, qf[mi][0], z, 0, 0, 0);
            z = __builtin_amdgcn_mfma_f32_16x16x32_bf16(kf1, qf[mi][1], z, 0, 0, 0);
            sc[mi][sub] = z;
          }
        }

        if (kt >= 2 * qt) {                    // diagonal tiles: causal mask
          const int koff = (kt - 2 * qt) * 64;
#pragma unroll
          for (int mi = 0; mi < 2; ++mi) {
            const int q_l = w * 32 + mi * 16 + c;
#pragma unroll
            for (int sub = 0; sub < 4; ++sub)
#pragma unroll
              for (int r = 0; r < 4; ++r)
                if (koff + sub * 16 + 4 * g + r > q_l) sc[mi][sub][r] = -INFINITY;
          }
        }

        float mx[2];
#pragma unroll
        for (int mi = 0; mi < 2; ++mi) {
          float v0 = fmaxf(fmaxf(sc[mi][0][0], sc[mi][0][1]), fmaxf(sc[mi][0][2], sc[mi][0][3]));
          float v1 = fmaxf(fmaxf(sc[mi][1][0], sc[mi][1][1]), fmaxf(sc[mi][1][2], sc[mi][1][3]));
          float v2 = fmaxf(fmaxf(sc[mi][2][0], sc[mi][2][1]), fmaxf(sc[mi][2][2], sc[mi][2][3]));
          float v3 = fmaxf(fmaxf(sc[mi][3][0], sc[mi][3][1]), fmaxf(sc[mi][3][2], sc[mi][3][3]));
          float v = fmaxf(fmaxf(v0, v1), fmaxf(v2, v3));
          v = fmaxf(v, __shfl_xor(v, 16));
          v = fmaxf(v, __shfl_xor(v, 32));
          mx[mi] = v;
        }

        bool need = (mx[0] > m_r[0] + 44.f) || (mx[1] > m_r[1] + 44.f);
        if (__any(need)) {
#pragma unroll
          for (int mi = 0; mi < 2; ++mi) {
            float mnew = fmaxf(m_r[mi], mx[mi]);
            float corr = __builtin_amdgcn_exp2f((m_r[mi] - mnew) * SCL);
            m_r[mi] = mnew;
            l_r[mi] *= corr;
#pragma unroll
            for (int ni = 0; ni < 4; ++ni) o_acc[mi][ni] *= corr;
          }
        }

        // P = exp2((s-m)*SCL) in regs; rowsum; pack via v_cvt_pk_bf16_f32
        bf16x8 pb[2][2];
#pragma unroll
        for (int mi = 0; mi < 2; ++mi) {
          const float a = -m_r[mi] * SCL;
          float s = 0.f;
#pragma unroll
          for (int sub = 0; sub < 4; ++sub)
#pragma unroll
            for (int r = 0; r < 4; ++r) {
              float e = __builtin_amdgcn_exp2f(fmaf(sc[mi][sub][r], SCL, a));
              sc[mi][sub][r] = e;
              s += e;
            }
          s += __shfl_xor(s, 16);
          s += __shfl_xor(s, 32);
          l_r[mi] += s;
          unsigned int* p32l = (unsigned int*)&pb[mi][0];
          unsigned int* p32h = (unsigned int*)&pb[mi][1];
#pragma unroll
          for (int jj = 0; jj < 4; ++jj) {
            const int sub = jj >> 1, r0 = (jj & 1) * 2;
            unsigned int lo_, hi_;
            asm("v_cvt_pk_bf16_f32 %0, %1, %2"
                : "=v"(lo_) : "v"(sc[mi][sub][r0]), "v"(sc[mi][sub][r0 + 1]));
            asm("v_cvt_pk_bf16_f32 %0, %1, %2"
                : "=v"(hi_) : "v"(sc[mi][2 + sub][r0]), "v"(sc[mi][2 + sub][r0 + 1]));
            p32l[jj] = lo_;
            p32h[jj] = hi_;
          }
        }

#pragma unroll
        for (int ni = 0; ni < 4; ++ni)
#pragma unroll
          for (int half = 0; half < 2; ++half) {
            bf16x8 vt = *(const bf16x8*)&Vs[cur][ni * 16 + c][h64 * 64 + half * 32 + g * 8];
#pragma unroll
            for (int mi = 0; mi < 2; ++mi)
              o_acc[mi][ni] = __builtin_amdgcn_mfma_f32_16x16x32_bf16(vt, pb[mi][half],
                                                                      o_acc[mi][ni], 0, 0, 0);
          }
      }  // h64

      // write prefetched epoch into the other buffer, then single barrier
      if (pr + 1 < npair) {
#pragma unroll
        for (int i = 0; i < 4; ++i) {
          int cid = i * 256 + t;
          *(uint4*)&Ks[cur ^ 1][cid >> 3][(cid & 7) * 8] = kr[i];
          *(uint4*)&Vs[cur ^ 1][cid >> 4][(cid & 15) * 8] = vr[i];
        }
      }
      __syncthreads();
    }

#pragma unroll
    for (int mi = 0; mi < 2; ++mi) {
      const float inv = 1.f / l_r[mi];
      const int q_g = q0 + w * 32 + mi * 16 + c;
      float* orow = out + (b * 2048 + q_g) * 1024 + h * 64;
#pragma unroll
      for (int ni = 0; ni < 4; ++ni) {
        f32x4 o = o_acc[mi][ni] * inv;
        *(f32x4*)(orow + ni * 16 + 4 * g) = o;
      }
    }
  }
}

// ---------------- launch ----------------
extern "C" void kernel_launch(void* const* d_in, const int* in_sizes, int n_in,
                              void* d_out, int out_size, void* d_ws, size_t ws_size,
                              hipStream_t stream) {
  const float* emb = (const float*)d_in[0];
  const float* Wq  = (const float*)d_in[1];
  const float* Wk  = (const float*)d_in[2];
  const float* Wv  = (const float*)d_in[3];
  char* ws = (char*)d_ws;
  unsigned short* Xb  = (unsigned short*)(ws + 0);          // 16,777,216
  unsigned short* Wt  = (unsigned short*)(ws + 16777216);   //  6,291,456
  unsigned short* Qb  = (unsigned short*)(ws + 23068672);   // 16,777,216
  unsigned short* Kb  = (unsigned short*)(ws + 39845888);   // 16,777,216
  unsigned short* Vtb = (unsigned short*)(ws + 56623104);   // 16,777,216
  float* out = (float*)d_out;

  convs<<<2816, 256, 0, stream>>>(emb, Wq, Wk, Wv, Xb, Wt);
  qkv_gemm<<<384, 512, 0, stream>>>(Xb, Wt, Qb, Kb, Vtb);
  attn<<<512, 256, 0, stream>>>(Qb, Kb, Vtb, out);
}

// Round 24
// 144.037 us; speedup vs baseline: 1.2353x; 1.2353x over previous
//
#include <hip/hip_runtime.h>

// Problem: B=4, S=2048, E=1024, H=16, DH=64
// out[b][s][h*64+d] = softmax_causal(Q K^T / 8) V, with Q/K/V = X @ W{q,k,v}[h]
//
// FINAL config (round-22 best = 144.2us; round-23's 128-key epochs reverted
// after a register-cliff spill storm, WRITE_SIZE 201MB):
//   1) convs:  merged conv_x (f32->bf16 X) + conv_w (W -> bf16 transposed Wt)
//   2) qkv_gemm: 256x256 tile, BK=32, 3-buffer LDS ring (96KB), counted
//        vmcnt(4), 1 barrier/tile, swizzled LDS, XCD-local grid. ALL p use
//        swapped-operand MFMA (C'=[n][m]); Q/K epilogue = uint2 stores;
//        p=2 V^T key-permuted scatter ([g|sub16|r] in 32-blocks).
//   3) attn: flash, swapped-QK^T (in-register P), permuted-k PV (single
//        ds_read_b128 per V fragment), K/V LDS double buffer (64-key tiles),
//        T14 reg prefetch, XCD-grouped grid, paired causal tiles {15-p, p},
//        cvt_pk P->bf16 pack (T12).

typedef short bf16x4 __attribute__((ext_vector_type(4)));
typedef short bf16x8 __attribute__((ext_vector_type(8)));
typedef float f32x4 __attribute__((ext_vector_type(4)));
typedef unsigned short u16x4 __attribute__((ext_vector_type(4)));
typedef unsigned short u16x8 __attribute__((ext_vector_type(8)));

#define SCL 0.1803368801111204f   /* log2(e)/8 : folds the 1/sqrt(64) into exp2 */

static __device__ __forceinline__ unsigned short f2bf(float f) {
  unsigned int u = __builtin_bit_cast(unsigned int, f);
  u += 0x7fffu + ((u >> 16) & 1u);   // RNE
  return (unsigned short)(u >> 16);
}

static __device__ __forceinline__ void gload16(const void* g, void* l) {
  __builtin_amdgcn_global_load_lds((__attribute__((address_space(1))) void*)g,
                                   (__attribute__((address_space(3))) void*)l, 16, 0, 0);
}

// ---------------- 1) merged convs ----------------
// blocks 0..767:    conv_w  (p = bid/256, h/et from bid%256)
// blocks 768..2815: conv_x  (grid-stride over 2M float4 chunks)
__global__ __launch_bounds__(256) void convs(const float* __restrict__ x,
                                             const float* __restrict__ Wq,
                                             const float* __restrict__ Wk,
                                             const float* __restrict__ Wv,
                                             unsigned short* __restrict__ Xb,
                                             unsigned short* __restrict__ Wt) {
  const int bid = blockIdx.x;
  const int t = threadIdx.x;
  if (bid < 768) {
    __shared__ __align__(16) unsigned short tile[64][72];  // [e][d], padded
    const int p = bid >> 8, he = bid & 255;
    const float* Wsrc = (p == 0) ? Wq : ((p == 1) ? Wk : Wv);
    const int h = he >> 4, et = he & 15;                   // 64-wide e tile
    const float* src = Wsrc + (h * 1024 + et * 64) * 64;   // rows e (64), cols d (64)
#pragma unroll
    for (int i = 0; i < 4; ++i) {
      int c = i * 256 + t;
      int r = c >> 4, cc = (c & 15) * 4;
      float4 v = *(const float4*)(src + r * 64 + cc);
      tile[r][cc + 0] = f2bf(v.x); tile[r][cc + 1] = f2bf(v.y);
      tile[r][cc + 2] = f2bf(v.z); tile[r][cc + 3] = f2bf(v.w);
    }
    __syncthreads();
#pragma unroll
    for (int i = 0; i < 2; ++i) {
      int c = i * 256 + t;
      int d = c >> 3, ec = (c & 7) * 8;
      u16x8 o;
#pragma unroll
      for (int j = 0; j < 8; ++j) o[j] = tile[ec + j][d];
      *(u16x8*)(Wt + (p * 1024 + h * 64 + d) * 1024 + et * 64 + ec) = o;
    }
  } else {
    const int n4 = 2097152;
    int i0 = (bid - 768) * 256 + t;
    const int stride = 2048 * 256;
    for (int c = i0; c < n4; c += stride) {
      float4 v = ((const float4*)x)[c];
      u16x4 o;
      o[0] = f2bf(v.x); o[1] = f2bf(v.y); o[2] = f2bf(v.z); o[3] = f2bf(v.w);
      ((u16x4*)Xb)[c] = o;
    }
  }
}

// ---------------- 2) QKV GEMM: 256x256, BK=32, 3-buf ring, unified swapped MFMA ----------------
// Grid 384 = 8 xcd x 4 m_local x 12 nt. 512 threads = 8 waves (2M x 4N),
// per-wave 128x64 out = acc[8][4] f32x4 (AGPRs). K = 1024 -> 32 K-tiles.
// Per K-tile: vmcnt(4) -> s_barrier -> {8 ds_read || stage A(kt+2)} ->
// 16 MFMA -> {4 ds_read || stage B(kt+2)} -> 16 MFMA. Compiler-counted lgkm
// waits; loads stay in flight across barriers (vmcnt(0) only at last tile).
// Swizzle: chunk_phys = chunk ^ (row&3) ^ ((row>>2)&3) on the pre-swizzled
// GLOBAL source (LDS dest linear, G21) and the same involution on ds_read.
// ALL p: mfma(bq, aq) -> C'[n][m]: n_g = nb0+wc*64+ni*16+g*4+r (r-contiguous
// d), m_g = m0+wr*128+mi*16+c16 (s). p<2: one uint2 (4 bf16) store per
// (mi,ni). p=2: V^T scatter with key permuted [g|sub16|r] in 32-blocks.
__global__ __launch_bounds__(512, 2) void qkv_gemm(const unsigned short* __restrict__ Xb,
                                                   const unsigned short* __restrict__ Wt,
                                                   unsigned short* __restrict__ Qb,
                                                   unsigned short* __restrict__ Kb,
                                                   unsigned short* __restrict__ Vtb) {
  __shared__ __align__(16) unsigned short L[3][2][256 * 32];  // [buf][A/B][row*32+chunk*8]

  const int t = threadIdx.x, lane = t & 63, w = t >> 6;
  const int wr = w >> 2, wc = w & 3, c16 = lane & 15, g = lane >> 4;

  const int bid = blockIdx.x;
  const int xcd = bid & 7, l = bid >> 3;        // l in 0..47
  const int nt = l >> 2;                        // 0..11
  const int m0 = (xcd * 4 + (l & 3)) * 256;     // XCD-local m stripe
  const int p = nt >> 2;                        // 0..2 (Q/K/V)
  const int nb0 = (nt & 3) * 256;               // n offset within the 1024 block

  f32x4 acc[8][4] = {};

  const int srow = t >> 2;
  const int scl = (t & 3) ^ ((srow & 3) ^ ((srow >> 2) & 3));  // pre-swizzled src chunk
  const int chp = (g ^ ((c16 & 3) ^ ((c16 >> 2) & 3))) * 8;

#define STAGE(KT, AB, HALF, BUF)                                                   \
  {                                                                                \
    const unsigned short* s_ =                                                     \
        (((AB) == 0) ? (Xb + (m0 + (HALF)*128) * 1024)                             \
                     : (Wt + (p * 1024 + nb0 + (HALF)*128) * 1024)) +              \
        (KT)*32 + srow * 1024 + scl * 8;                                           \
    gload16(s_, &L[BUF][AB][(HALF)*4096 + w * 512]);                               \
  }
#define LDA(BUF, MI) (*(const bf16x8*)&L[BUF][0][(wr * 128 + (MI)*16 + c16) * 32 + chp])
#define LDB(BUF, NI) (*(const bf16x8*)&L[BUF][1][(wc * 64 + (NI)*16 + c16) * 32 + chp])

  // prologue: stage tiles 0 (buf0) and 1 (buf1); 8 loads in flight
  STAGE(0, 0, 0, 0); STAGE(0, 0, 1, 0); STAGE(0, 1, 0, 0); STAGE(0, 1, 1, 0);
  STAGE(1, 0, 0, 1); STAGE(1, 0, 1, 1); STAGE(1, 1, 0, 1); STAGE(1, 1, 1, 1);

  int buf = 0;
#pragma unroll 1
  for (int kt = 0; kt < 32; ++kt) {
    const int sbuf = (buf == 0) ? 2 : buf - 1;  // slot of kt-1, freed by this barrier
    if (kt < 31) { asm volatile("s_waitcnt vmcnt(4)" ::: "memory"); }  // tile kt landed
    else         { asm volatile("s_waitcnt vmcnt(0)" ::: "memory"); }
    __builtin_amdgcn_s_barrier();

    bf16x8 bq[4], aq[4];
#pragma unroll
    for (int ni = 0; ni < 4; ++ni) bq[ni] = LDB(buf, ni);
#pragma unroll
    for (int mi = 0; mi < 4; ++mi) aq[mi] = LDA(buf, mi);
    if (kt < 30) { STAGE(kt + 2, 0, 0, sbuf); STAGE(kt + 2, 0, 1, sbuf); }
    __builtin_amdgcn_s_setprio(1);
#pragma unroll
    for (int q = 0; q < 4; ++q)
#pragma unroll
      for (int ni = 0; ni < 4; ++ni)
        acc[q][ni] = __builtin_amdgcn_mfma_f32_16x16x32_bf16(bq[ni], aq[q], acc[q][ni], 0, 0, 0);
    __builtin_amdgcn_s_setprio(0);

    bf16x8 aq2[4];
#pragma unroll
    for (int mi = 0; mi < 4; ++mi) aq2[mi] = LDA(buf, 4 + mi);
    if (kt < 30) { STAGE(kt + 2, 1, 0, sbuf); STAGE(kt + 2, 1, 1, sbuf); }
    __builtin_amdgcn_s_setprio(1);
#pragma unroll
    for (int q = 0; q < 4; ++q)
#pragma unroll
      for (int ni = 0; ni < 4; ++ni)
        acc[4 + q][ni] = __builtin_amdgcn_mfma_f32_16x16x32_bf16(bq[ni], aq2[q], acc[4 + q][ni], 0, 0, 0);
    __builtin_amdgcn_s_setprio(0);

    buf = (buf == 2) ? 0 : buf + 1;
  }

  // epilogue: C'[n][m] layout (n over g*4+r, m over c16)
  if (p != 2) {
    unsigned short* dst = (p == 0) ? Qb : Kb;
#pragma unroll
    for (int mi = 0; mi < 8; ++mi) {
      const int m_g = m0 + wr * 128 + mi * 16 + c16;              // s-dim
      const int b = m_g >> 11, s = m_g & 2047;
#pragma unroll
      for (int ni = 0; ni < 4; ++ni) {
        const int n_g0 = nb0 + wc * 64 + ni * 16 + g * 4;         // d base, r contig
        unsigned int w0, w1;
        asm("v_cvt_pk_bf16_f32 %0, %1, %2"
            : "=v"(w0) : "v"(acc[mi][ni][0]), "v"(acc[mi][ni][1]));
        asm("v_cvt_pk_bf16_f32 %0, %1, %2"
            : "=v"(w1) : "v"(acc[mi][ni][2]), "v"(acc[mi][ni][3]));
        uint2 pk; pk.x = w0; pk.y = w1;
        *(uint2*)(dst + ((b * 16 + (n_g0 >> 6)) * 2048 + s) * 64 + (n_g0 & 63)) = pk;
      }
    }
  } else {
#pragma unroll
    for (int mi = 0; mi < 8; ++mi)
#pragma unroll
      for (int ni = 0; ni < 4; ++ni)
#pragma unroll
        for (int r = 0; r < 4; ++r) {
          int n_g = nb0 + wc * 64 + ni * 16 + g * 4 + r;          // d-dim
          int m_g = m0 + wr * 128 + mi * 16 + c16;                // s-dim
          int b = m_g >> 11, s = m_g & 2047;
          // key permuted within 32-block: [g(2b) | sub16(1b) | r(2b)]
          int sp = (s & ~31) | ((s << 1) & 24) | ((s >> 2) & 4) | (s & 3);
          Vtb[((b * 16 + (n_g >> 6)) * 64 + (n_g & 63)) * 2048 + sp] = f2bf(acc[mi][ni][r]);
        }
  }
#undef STAGE
#undef LDA
#undef LDB
}

// ---------------- 3) Flash attention (swapped-QK^T, in-register P, cvt_pk pack) ----------------
// 1D grid 512. xcd = bid&7; 8 heads/XCD; 8 pair-blocks/head; pair p: {15-p, p}.
// 4 waves x 32 q-rows (mi=2 x 16). 64-key tiles. K/V double-buffered, 1 barrier/tile.
// V^T arrives key-permuted (32-block internal [g|sub16|r]) -> PV fragment is
// ONE ds_read_b128 at [ni*16+c][half*32+g*8].
__global__ __launch_bounds__(256) void attn(const unsigned short* __restrict__ Qb,
                                            const unsigned short* __restrict__ Kb,
                                            const unsigned short* __restrict__ Vtb,
                                            float* __restrict__ out) {
  const int bid = blockIdx.x;
  const int xcd = bid & 7, slot = bid >> 3;
  const int bh = xcd * 8 + (slot >> 3);
  const int pp = slot & 7;
  const int b = bh >> 4, h = bh & 15;
  const int t = threadIdx.x, lane = t & 63, w = t >> 6;
  const int g = lane >> 4, c = lane & 15;

  __shared__ __align__(16) unsigned short Ks[2][64][72];  // [buf][key][d] padded
  __shared__ __align__(16) unsigned short Vs[2][64][72];  // [buf][d][key-perm] padded

  for (int job = 0; job < 2; ++job) {
    const int qt = job ? pp : 15 - pp;
    const int q0 = qt * 128;
    const int ktiles = 2 * qt + 2;

    bf16x8 qf[2][2];
#pragma unroll
    for (int mi = 0; mi < 2; ++mi)
#pragma unroll
      for (int kc = 0; kc < 2; ++kc)
        qf[mi][kc] = *(const bf16x8*)(Qb + ((bh * 2048 + q0 + w * 32 + mi * 16 + c) << 6)
                                         + kc * 32 + g * 8);

    f32x4 o_acc[2][4] = {};
    float m_r[2] = {-INFINITY, -INFINITY};
    float l_r[2] = {0.f, 0.f};

    uint4 kr[2], vr[2];
#pragma unroll
    for (int i = 0; i < 2; ++i) {
      int cid = i * 256 + t;
      kr[i] = *(const uint4*)(Kb + ((bh * 2048) << 6) + cid * 8);
      vr[i] = *(const uint4*)(Vtb + ((bh * 64 + (cid >> 3)) << 11) + (cid & 7) * 8);
    }
#pragma unroll
    for (int i = 0; i < 2; ++i) {
      int cid = i * 256 + t;
      *(uint4*)&Ks[0][cid >> 3][(cid & 7) * 8] = kr[i];
      *(uint4*)&Vs[0][cid >> 3][(cid & 7) * 8] = vr[i];
    }
    __syncthreads();

    for (int kt = 0; kt < ktiles; ++kt) {
      const int cur = kt & 1;
      if (kt + 1 < ktiles) {
        const int kv0n = (kt + 1) * 64;
#pragma unroll
        for (int i = 0; i < 2; ++i) {
          int cid = i * 256 + t;
          kr[i] = *(const uint4*)(Kb + ((bh * 2048 + kv0n) << 6) + cid * 8);
          vr[i] = *(const uint4*)(Vtb + ((bh * 64 + (cid >> 3)) << 11) + kv0n + (cid & 7) * 8);
        }
      }

      f32x4 sc[2][4];
#pragma unroll
      for (int sub = 0; sub < 4; ++sub) {
        bf16x8 kf0 = *(const bf16x8*)&Ks[cur][sub * 16 + c][g * 8];
        bf16x8 kf1 = *(const bf16x8*)&Ks[cur][sub * 16 + c][32 + g * 8];
#pragma unroll
        for (int mi = 0; mi < 2; ++mi) {
          f32x4 z = {};
          z = __builtin_amdgcn_mfma_f32_16x16x32_bf16(kf0, qf[mi][0], z, 0, 0, 0);
          z = __builtin_amdgcn_mfma_f32_16x16x32_bf16(kf1, qf[mi][1], z, 0, 0, 0);
          sc[mi][sub] = z;
        }
      }

      if (kt >= 2 * qt) {
        const int koff = (kt - 2 * qt) * 64;
#pragma unroll
        for (int mi = 0; mi < 2; ++mi) {
          const int q_l = w * 32 + mi * 16 + c;
#pragma unroll
          for (int sub = 0; sub < 4; ++sub)
#pragma unroll
            for (int r = 0; r < 4; ++r)
              if (koff + sub * 16 + 4 * g + r > q_l) sc[mi][sub][r] = -INFINITY;
        }
      }

      float mx[2];
#pragma unroll
      for (int mi = 0; mi < 2; ++mi) {
        float v0 = fmaxf(fmaxf(sc[mi][0][0], sc[mi][0][1]), fmaxf(sc[mi][0][2], sc[mi][0][3]));
        float v1 = fmaxf(fmaxf(sc[mi][1][0], sc[mi][1][1]), fmaxf(sc[mi][1][2], sc[mi][1][3]));
        float v2 = fmaxf(fmaxf(sc[mi][2][0], sc[mi][2][1]), fmaxf(sc[mi][2][2], sc[mi][2][3]));
        float v3 = fmaxf(fmaxf(sc[mi][3][0], sc[mi][3][1]), fmaxf(sc[mi][3][2], sc[mi][3][3]));
        float v = fmaxf(fmaxf(v0, v1), fmaxf(v2, v3));
        v = fmaxf(v, __shfl_xor(v, 16));
        v = fmaxf(v, __shfl_xor(v, 32));
        mx[mi] = v;
      }

      bool need = (mx[0] > m_r[0] + 44.f) || (mx[1] > m_r[1] + 44.f);
      if (__any(need)) {
#pragma unroll
        for (int mi = 0; mi < 2; ++mi) {
          float mnew = fmaxf(m_r[mi], mx[mi]);
          float corr = __builtin_amdgcn_exp2f((m_r[mi] - mnew) * SCL);
          m_r[mi] = mnew;
          l_r[mi] *= corr;
#pragma unroll
          for (int ni = 0; ni < 4; ++ni) o_acc[mi][ni] *= corr;
        }
      }

      // P = exp2((s-m)*SCL) in regs; rowsum in regs; pack via v_cvt_pk_bf16_f32
      bf16x8 pb[2][2];
#pragma unroll
      for (int mi = 0; mi < 2; ++mi) {
        const float a = -m_r[mi] * SCL;
        float s = 0.f;
#pragma unroll
        for (int sub = 0; sub < 4; ++sub)
#pragma unroll
          for (int r = 0; r < 4; ++r) {
            float e = __builtin_amdgcn_exp2f(fmaf(sc[mi][sub][r], SCL, a));
            sc[mi][sub][r] = e;
            s += e;
          }
        s += __shfl_xor(s, 16);
        s += __shfl_xor(s, 32);
        l_r[mi] += s;
        unsigned int* p32l = (unsigned int*)&pb[mi][0];
        unsigned int* p32h = (unsigned int*)&pb[mi][1];
#pragma unroll
        for (int jj = 0; jj < 4; ++jj) {
          const int sub = jj >> 1, r0 = (jj & 1) * 2;
          unsigned int lo_, hi_;
          asm("v_cvt_pk_bf16_f32 %0, %1, %2"
              : "=v"(lo_) : "v"(sc[mi][sub][r0]), "v"(sc[mi][sub][r0 + 1]));
          asm("v_cvt_pk_bf16_f32 %0, %1, %2"
              : "=v"(hi_) : "v"(sc[mi][2 + sub][r0]), "v"(sc[mi][2 + sub][r0 + 1]));
          p32l[jj] = lo_;
          p32h[jj] = hi_;
        }
      }

#pragma unroll
      for (int ni = 0; ni < 4; ++ni)
#pragma unroll
        for (int half = 0; half < 2; ++half) {
          bf16x8 vt = *(const bf16x8*)&Vs[cur][ni * 16 + c][half * 32 + g * 8];
#pragma unroll
          for (int mi = 0; mi < 2; ++mi)
            o_acc[mi][ni] = __builtin_amdgcn_mfma_f32_16x16x32_bf16(vt, pb[mi][half],
                                                                    o_acc[mi][ni], 0, 0, 0);
        }

      if (kt + 1 < ktiles) {
#pragma unroll
        for (int i = 0; i < 2; ++i) {
          int cid = i * 256 + t;
          *(uint4*)&Ks[cur ^ 1][cid >> 3][(cid & 7) * 8] = kr[i];
          *(uint4*)&Vs[cur ^ 1][cid >> 3][(cid & 7) * 8] = vr[i];
        }
      }
      __syncthreads();
    }

#pragma unroll
    for (int mi = 0; mi < 2; ++mi) {
      const float inv = 1.f / l_r[mi];
      const int q_g = q0 + w * 32 + mi * 16 + c;
      float* orow = out + (b * 2048 + q_g) * 1024 + h * 64;
#pragma unroll
      for (int ni = 0; ni < 4; ++ni) {
        f32x4 o = o_acc[mi][ni] * inv;
        *(f32x4*)(orow + ni * 16 + 4 * g) = o;
      }
    }
  }
}

// ---------------- launch ----------------
extern "C" void kernel_launch(void* const* d_in, const int* in_sizes, int n_in,
                              void* d_out, int out_size, void* d_ws, size_t ws_size,
                              hipStream_t stream) {
  const float* emb = (const float*)d_in[0];
  const float* Wq  = (const float*)d_in[1];
  const float* Wk  = (const float*)d_in[2];
  const float* Wv  = (const float*)d_in[3];
  char* ws = (char*)d_ws;
  unsigned short* Xb  = (unsigned short*)(ws + 0);          // 16,777,216
  unsigned short* Wt  = (unsigned short*)(ws + 16777216);   //  6,291,456
  unsigned short* Qb  = (unsigned short*)(ws + 23068672);   // 16,777,216
  unsigned short* Kb  = (unsigned short*)(ws + 39845888);   // 16,777,216
  unsigned short* Vtb = (unsigned short*)(ws + 56623104);   // 16,777,216
  float* out = (float*)d_out;

  convs<<<2816, 256, 0, stream>>>(emb, Wq, Wk, Wv, Xb, Wt);
  qkv_gemm<<<384, 512, 0, stream>>>(Xb, Wt, Qb, Kb, Vtb);
  attn<<<512, 256, 0, stream>>>(Qb, Kb, Vtb, out);
}